// Round 7
// baseline (94.799 us; speedup 1.0000x reference)
//
#include <hip/hip_runtime.h>
#include <hip/hip_fp16.h>

constexpr int W = 128, H = 256, ITERS = 24, B = 256, K_IN = 784, NC = 10;
constexpr int NPK = 72;   // per-thread packed half2 weight words (registers)
constexpr float NLOG2E = -1.4426950408889634f;   // fold sigmoid exp->exp2 into weights
constexpr int PUB_ROWS = 68;                     // 2+64+2 halo slots
constexpr int PUB_HALFS = PUB_ROWS * 256;

// Rebuilt fully on every launch; no cross-call state read before write.
__device__ __half2 g_PKW[NPK * 1024];   // [word][tid]
__device__ float g_pre[B * H];

// Thread map (build_pack and grid_iter must agree):
//   p = tid>>6 (wave), lane = tid&63; main rows w = 8p..8p+7, cols h = 4*lane..4*lane+3.
//   Ghost rows q = 8p-1 (slot s=0) and q = 8p+8 (s=9); main row rw has slot s=rw+1.
// All weights pre-scaled by NLOG2E; out-of-domain rows/cols get ZERO weights.
//   pk[i*2+jj], i=0..10: hw row 8p-2+i, col pair jj (hwS(wp,h)=hw[wp*256+h] if 0<=wp<=126 else 0)
//     update of slot s uses wL = pk[2s+jj], wR = pk[2s+2+jj]
//   pk[22+s]: vA=(V(q,h0),V(q,h0+1)); pk[32+s]: vB=(V(q,h0+2),V(q,h0+3));
//   pk[42+s]: vT=(V(q,h0+3),V(q,h0+4)); pk[52+2s+jj]: bias pairs
//   where V(q,m)=vw[q*255+m-1] if (0<=q<=127 && 1<=m<=255) else 0
__global__ void build_pack(const float* __restrict__ hw, const float* __restrict__ vw,
                           const float* __restrict__ hbp, const float* __restrict__ vbp) {
    const int t = blockIdx.x * 64 + threadIdx.x;   // 16 x 64 = 1024
    const int p = t >> 6, lane = t & 63;
    const int w8 = p * 8, h0 = lane * 4;

    auto HWS = [&](int wp, int h) -> float {
        return (wp >= 0 && wp <= W - 2) ? hw[wp * H + h] : 0.f;
    };
    auto VVg = [&](int q, int m) -> float {
        return (q >= 0 && q <= W - 1 && m >= 1 && m <= H - 1) ? vw[q * (H - 1) + m - 1] : 0.f;
    };

    for (int i = 0; i < 11; ++i) {
        const int wp = w8 - 2 + i;
        for (int jj = 0; jj < 2; ++jj) {
            const int h = h0 + 2 * jj;
            g_PKW[(i * 2 + jj) * 1024 + t] =
                __floats2half2_rn(NLOG2E * HWS(wp, h), NLOG2E * HWS(wp, h + 1));
        }
    }
    for (int s = 0; s < 10; ++s) {
        const int q = w8 - 1 + s;
        g_PKW[(22 + s) * 1024 + t] =
            __floats2half2_rn(NLOG2E * VVg(q, h0), NLOG2E * VVg(q, h0 + 1));
        g_PKW[(32 + s) * 1024 + t] =
            __floats2half2_rn(NLOG2E * VVg(q, h0 + 2), NLOG2E * VVg(q, h0 + 3));
        g_PKW[(42 + s) * 1024 + t] =
            __floats2half2_rn(NLOG2E * VVg(q, h0 + 3), NLOG2E * VVg(q, h0 + 4));
        const bool qv = (q >= 0 && q <= W - 1);
        for (int jj = 0; jj < 2; ++jj) {
            float sb[2];
            for (int mm = 0; mm < 2; ++mm) {
                const int h = h0 + 2 * jj + mm;
                float v = 0.f;
                if (qv) {
                    if (q >= 1)     v += hbp[(q - 1) * H + h];
                    if (q <= W - 2) v += hbp[q * H + h];
                    if (h >= 1)     v += vbp[q * (H - 1) + h - 1];
                    if (h <= H - 2) v += vbp[q * (H - 1) + h];
                }
                sb[mm] = NLOG2E * v;
            }
            g_PKW[(52 + 2 * s + jj) * 1024 + t] = __floats2half2_rn(sb[0], sb[1]);
        }
    }
}

__global__ void pre_gemm(const float* __restrict__ x, const float* __restrict__ w_pre,
                         const float* __restrict__ b_pre) {
    __shared__ float xs[K_IN];
    __shared__ float part[1024];
    const int b = blockIdx.x, tid = threadIdx.x;
    for (int k = tid; k < K_IN; k += 1024) xs[k] = x[b * K_IN + k];
    __syncthreads();
    {
        const int j = tid & 255, chunk = tid >> 8;     // 4 chunks x 196
        const float* wp = w_pre + j;
        const int k0 = chunk * 196;
        float acc = 0.f;
#pragma unroll 4
        for (int k = 0; k < 196; ++k) acc += xs[k0 + k] * wp[(k0 + k) * H];
        part[chunk * 256 + j] = acc;
    }
    __syncthreads();
    if (tid < 256)
        g_pre[b * H + tid] = b_pre[tid] + part[tid] + part[256 + tid]
                           + part[512 + tid] + part[768 + tid];
}

__device__ __forceinline__ unsigned h2u(__half2 v) { return __builtin_bit_cast(unsigned, v); }
__device__ __forceinline__ __half2 u2h(unsigned v) { return __builtin_bit_cast(__half2, v); }

// One cell-row update for weight slot S. Writes sigmoid result to OUTA/OUTB.
#define CELLSTEP(S, PMA, PMB, NXA, NXB, P1, P2, P3, OUTA, OUTB)                    \
    {                                                                              \
        const __half2 vA_ = pk[22 + (S)], vB_ = pk[32 + (S)], vT_ = pk[42 + (S)];  \
        const __half2 vS_ = __halves2half2(__high2half(vA_), __low2half(vB_));     \
        __half2 ya = pk[52 + 2 * (S)];                                             \
        ya = __hfma2(pk[2 * (S)],     PMA,     ya);                                \
        ya = __hfma2(pk[2 * (S) + 2], NXA,     ya);                                \
        ya = __hfma2(vA_,             u2h(P1), ya);                                \
        ya = __hfma2(vS_,             u2h(P2), ya);                                \
        __half2 yb = pk[53 + 2 * (S)];                                             \
        yb = __hfma2(pk[2 * (S) + 1], PMB,     yb);                                \
        yb = __hfma2(pk[2 * (S) + 3], NXB,     yb);                                \
        yb = __hfma2(vB_,             u2h(P2), yb);                                \
        yb = __hfma2(vT_,             u2h(P3), yb);                                \
        OUTA = h2rcp(__hadd2(one2, h2exp2(ya)));                                   \
        OUTB = h2rcp(__hadd2(one2, h2exp2(yb)));                                   \
    }

// Main row RW (slot RW+1) using LU/RD lane-edge packs; carries pm through pmA/pmB.
#define MROW(RW, NXA, NXB)                                                          \
    {                                                                               \
        const __half2 c2a = a2[2 * (RW)], c2b = a2[2 * (RW) + 1];                   \
        const unsigned P1 = __builtin_amdgcn_perm(h2u(c2a), LU[(RW) >> 1],          \
                              ((RW) & 1) ? 0x05040302u : 0x05040100u);              \
        const unsigned P2 = __builtin_amdgcn_perm(h2u(c2b), h2u(c2a), 0x05040302u); \
        const unsigned P3 = __builtin_amdgcn_perm(RD[(RW) >> 1], h2u(c2b),          \
                              ((RW) & 1) ? 0x07060302u : 0x05040302u);              \
        CELLSTEP((RW) + 1, pmA, pmB, NXA, NXB, P1, P2, P3,                          \
                 a2[2 * (RW)], a2[2 * (RW) + 1]);                                   \
        pmA = c2a; pmB = c2b;                                                       \
    }

// Snapshot lane-edge words from current a2 (2 rows packed per bpermute).
#define LUPACK                                                                         \
    _Pragma("unroll")                                                                  \
    for (int k = 0; k < 4; ++k) {                                                      \
        const unsigned uw =                                                            \
            __builtin_amdgcn_perm(h2u(a2[4 * k + 3]), h2u(a2[4 * k + 1]), 0x07060302u);\
        const unsigned dw =                                                            \
            __builtin_amdgcn_perm(h2u(a2[4 * k + 2]), h2u(a2[4 * k]),     0x05040100u);\
        LU[k] = __builtin_amdgcn_ds_bpermute(addr_up, uw);                             \
        RD[k] = __builtin_amdgcn_ds_bpermute(addr_dn, dw);                             \
    }

__global__ void __launch_bounds__(1024, 4)
grid_iter(const float* __restrict__ w_out, const float* __restrict__ b_out,
          float* __restrict__ out) {
    // Double-buffered 2-deep halo: per wave 4 published rows {0,1,6,7}.
    // Wave p slots: 2+4p..5+4p. Reader p: hl6=4p, hl7=4p+1, hr0=4p+6, hr1=4p+7.
    // Slots {0,1,66,67} permanent zeros.
    __shared__ __half pub[2 * PUB_HALFS];   // 69632 B

    const int tid = threadIdx.x, b = blockIdx.x;
    const int p = tid >> 6, lane = tid & 63;
    const int h0 = lane * 4;

    __half2 pk[NPK];
#pragma unroll
    for (int i = 0; i < NPK; ++i) pk[i] = g_PKW[i * 1024 + tid];

    // zero border slots (both buffers)
    for (int i = tid; i < 4 * 256; i += 1024) {
        const int k = i >> 8, c = i & 255;
        const int sl = (k < 2) ? k : 64 + k;     // 0,1,66,67
        pub[sl * 256 + c] = __float2half(0.f);
        pub[PUB_HALFS + sl * 256 + c] = __float2half(0.f);
    }

    __half2 a2[16];   // main rows rw=0..7, 2 half2 each (cols h0..h0+3)
#pragma unroll
    for (int i = 0; i < 16; ++i) a2[i] = __floats2half2_rn(0.f, 0.f);
    if (p == 0) {
        const float4 pr = *(const float4*)&g_pre[b * H + h0];
        a2[0] = __floats2half2_rn(pr.x, pr.y);
        a2[1] = __floats2half2_rn(pr.z, pr.w);
    }

    const __half2 one2 = __floats2half2_rn(1.f, 1.f);
    const int addr_up = (lane - 1) << 2;   // bpermute wraps mod 64; edge garbage hits 0-weights
    const int addr_dn = (lane + 1) << 2;
    unsigned LU[4], RD[4];

    // initial publish into buffer 0
    {
        __half* pn = pub;
        *(uint2*)(pn + (4 * p + 2) * 256 + h0) = make_uint2(h2u(a2[0]),  h2u(a2[1]));
        *(uint2*)(pn + (4 * p + 3) * 256 + h0) = make_uint2(h2u(a2[2]),  h2u(a2[3]));
        *(uint2*)(pn + (4 * p + 4) * 256 + h0) = make_uint2(h2u(a2[12]), h2u(a2[13]));
        *(uint2*)(pn + (4 * p + 5) * 256 + h0) = make_uint2(h2u(a2[14]), h2u(a2[15]));
    }
    __syncthreads();

    for (int blk = 0; blk < ITERS / 2; ++blk) {
        __half* pw = pub + (blk & 1) * PUB_HALFS;
        __half* pn = pub + ((blk + 1) & 1) * PUB_HALFS;

        // halo values (old rows 8p-2, 8p-1, 8p+8, 8p+9) + lane-edge halves of hl7/hr0
        const uint2 l6 = *(const uint2*)(pw + (4 * p)     * 256 + h0);
        const uint2 l7 = *(const uint2*)(pw + (4 * p + 1) * 256 + h0);
        const uint2 r0 = *(const uint2*)(pw + (4 * p + 6) * 256 + h0);
        const uint2 r1 = *(const uint2*)(pw + (4 * p + 7) * 256 + h0);
        const __half eLl = pw[(4 * p + 1) * 256 + h0 - 1];
        const __half eRl = pw[(4 * p + 1) * 256 + h0 + 4];
        const __half eLh = pw[(4 * p + 6) * 256 + h0 - 1];
        const __half eRh = pw[(4 * p + 6) * 256 + h0 + 4];

        LUPACK;   // lane edges of OLD a2

        // ---- iter A: ghosts first (need old a2), then rows 0..7 ----
        __half2 glA, glB, ghA, ghB;
        {   // ghost-low q=8p-1 (slot 0): pm=hl6, c=hl7, nx=old row0
            const __half2 cA = u2h(l7.x), cB = u2h(l7.y);
            const unsigned P1 = h2u(__halves2half2(eLl, __low2half(cA)));
            const unsigned P2 = h2u(__halves2half2(__high2half(cA), __low2half(cB)));
            const unsigned P3 = h2u(__halves2half2(__high2half(cB), eRl));
            CELLSTEP(0, u2h(l6.x), u2h(l6.y), a2[0], a2[1], P1, P2, P3, glA, glB);
        }
        {   // ghost-high q=8p+8 (slot 9): pm=old row7, c=hr0, nx=hr1
            const __half2 cA = u2h(r0.x), cB = u2h(r0.y);
            const unsigned P1 = h2u(__halves2half2(eLh, __low2half(cA)));
            const unsigned P2 = h2u(__halves2half2(__high2half(cA), __low2half(cB)));
            const unsigned P3 = h2u(__halves2half2(__high2half(cB), eRh));
            CELLSTEP(9, a2[14], a2[15], u2h(r1.x), u2h(r1.y), P1, P2, P3, ghA, ghB);
        }
        {
            __half2 pmA = u2h(l7.x), pmB = u2h(l7.y);
            MROW(0, a2[2],  a2[3]);
            MROW(1, a2[4],  a2[5]);
            MROW(2, a2[6],  a2[7]);
            MROW(3, a2[8],  a2[9]);
            MROW(4, a2[10], a2[11]);
            MROW(5, a2[12], a2[13]);
            MROW(6, a2[14], a2[15]);
            MROW(7, u2h(r0.x), u2h(r0.y));
        }

        // ---- iter B: registers only ----
        LUPACK;   // lane edges of NEW a2
        {
            __half2 pmA = glA, pmB = glB;
            MROW(0, a2[2],  a2[3]);
            MROW(1, a2[4],  a2[5]);
            MROW(2, a2[6],  a2[7]);
            MROW(3, a2[8],  a2[9]);
            MROW(4, a2[10], a2[11]);
            MROW(5, a2[12], a2[13]);
            MROW(6, a2[14], a2[15]);
            MROW(7, ghA, ghB);
        }

        // publish rows {0,1,6,7} for the next block
        *(uint2*)(pn + (4 * p + 2) * 256 + h0) = make_uint2(h2u(a2[0]),  h2u(a2[1]));
        *(uint2*)(pn + (4 * p + 3) * 256 + h0) = make_uint2(h2u(a2[2]),  h2u(a2[3]));
        *(uint2*)(pn + (4 * p + 4) * 256 + h0) = make_uint2(h2u(a2[12]), h2u(a2[13]));
        *(uint2*)(pn + (4 * p + 5) * 256 + h0) = make_uint2(h2u(a2[14]), h2u(a2[15]));
        __syncthreads();
    }

    // out[b] = act[w=126] @ w_out + b_out ; w=126 is p=15, rw=6 -> a2[12..13]
    if (p == 15) {
        const float2 u0 = __half22float2(a2[12]), u1 = __half22float2(a2[13]);
        const float av[4] = {u0.x, u0.y, u1.x, u1.y};
        float acc[NC];
#pragma unroll
        for (int c = 0; c < NC; ++c) acc[c] = 0.f;
#pragma unroll
        for (int j = 0; j < 4; ++j) {
            const float* wr = w_out + (h0 + j) * NC;
#pragma unroll
            for (int c = 0; c < NC; ++c) acc[c] += av[j] * wr[c];
        }
#pragma unroll
        for (int off = 32; off >= 1; off >>= 1)
#pragma unroll
            for (int c = 0; c < NC; ++c) acc[c] += __shfl_down(acc[c], off, 64);
        if (lane == 0) {
#pragma unroll
            for (int c = 0; c < NC; ++c) out[b * NC + c] = acc[c] + b_out[c];
        }
    }
}

extern "C" void kernel_launch(void* const* d_in, const int* in_sizes, int n_in,
                              void* d_out, int out_size, void* d_ws, size_t ws_size,
                              hipStream_t stream) {
    const float* x     = (const float*)d_in[0];
    const float* w_pre = (const float*)d_in[1];
    const float* b_pre = (const float*)d_in[2];
    const float* hw    = (const float*)d_in[3];
    const float* vw    = (const float*)d_in[4];
    const float* hb    = (const float*)d_in[5];
    const float* vb    = (const float*)d_in[6];
    const float* w_out = (const float*)d_in[7];
    const float* b_out = (const float*)d_in[8];
    float* out = (float*)d_out;

    hipLaunchKernelGGL(build_pack, dim3(16), dim3(64), 0, stream, hw, vw, hb, vb);
    hipLaunchKernelGGL(pre_gemm, dim3(B), dim3(1024), 0, stream, x, w_pre, b_pre);
    hipLaunchKernelGGL(grid_iter, dim3(B), dim3(1024), 0, stream, w_out, b_out, out);
}

// Round 9
// 84.397 us; speedup vs baseline: 1.1232x; 1.1232x over previous
//
#include <hip/hip_runtime.h>
#include <hip/hip_fp16.h>

constexpr int W = 128, H = 256, ITERS = 24, B = 256, K_IN = 784, NC = 10;
constexpr int NPK = 66;   // per-thread packed half2 weight words (registers)
constexpr float NLOG2E = -1.4426950408889634f;   // fold sigmoid exp->exp2 into weights
constexpr int PUB_ROWS = 34;                     // 1+32+1 halo slots
constexpr int PUB_HALFS = PUB_ROWS * 256;

// Rebuilt fully on every launch; no cross-call state read before write.
__device__ __half2 g_PKW[NPK * 1024];   // [word][tid]

// Thread map (build_pack and grid_iter must agree):
//   p = tid>>6 (wave), lane = tid&63; rows w = 8p..8p+7, cols h = 4*lane..4*lane+3.
// All values pre-scaled by NLOG2E. With V(w,m) = vw[w*255+m-1] for 1<=m<=255 else 0,
// hwS(wp,h) = hw[wp*256+h] for 0<=wp<=126 else 0:
//   word 2i+jj (i=0..8, jj=0..1): ( hwS(8p-1+i, h0+2jj), hwS(8p-1+i, h0+2jj+1) )
//   18+rw: vA=(V(w,h0),V(w,h0+1))   26+rw: vB=(V(w,h0+2),V(w,h0+3))
//   34+rw: vS=(V(w,h0+1),V(w,h0+2)) 42+rw: vT=(V(w,h0+3),V(w,h0+4))
//   50+2rw+jj: bias-sum pairs
__global__ void build_pack(const float* __restrict__ hw, const float* __restrict__ vw,
                           const float* __restrict__ hbp, const float* __restrict__ vbp) {
    const int t = blockIdx.x * blockDim.x + threadIdx.x;   // 16 x 64 = 1024
    if (t >= 1024) return;
    const int p = t >> 6, lane = t & 63;
    const int w8 = p * 8, h0 = lane * 4;

    auto HWS = [&](int wp, int h) -> float {
        return (wp >= 0 && wp <= W - 2) ? hw[wp * H + h] : 0.f;
    };
    auto VV = [&](int w, int m) -> float {
        return (m >= 1 && m <= H - 1) ? vw[w * (H - 1) + m - 1] : 0.f;
    };

    for (int i = 0; i < 9; ++i)
        for (int jj = 0; jj < 2; ++jj) {
            const int wp = w8 - 1 + i, h = h0 + 2 * jj;
            g_PKW[(i * 2 + jj) * 1024 + t] =
                __floats2half2_rn(NLOG2E * HWS(wp, h), NLOG2E * HWS(wp, h + 1));
        }
    for (int rw = 0; rw < 8; ++rw) {
        const int w = w8 + rw;
        g_PKW[(18 + rw) * 1024 + t] =
            __floats2half2_rn(NLOG2E * VV(w, h0), NLOG2E * VV(w, h0 + 1));
        g_PKW[(26 + rw) * 1024 + t] =
            __floats2half2_rn(NLOG2E * VV(w, h0 + 2), NLOG2E * VV(w, h0 + 3));
        g_PKW[(34 + rw) * 1024 + t] =
            __floats2half2_rn(NLOG2E * VV(w, h0 + 1), NLOG2E * VV(w, h0 + 2));
        g_PKW[(42 + rw) * 1024 + t] =
            __floats2half2_rn(NLOG2E * VV(w, h0 + 3), NLOG2E * VV(w, h0 + 4));
        for (int jj = 0; jj < 2; ++jj) {
            float s[2];
            for (int mm = 0; mm < 2; ++mm) {
                const int h = h0 + 2 * jj + mm;
                float v = 0.f;
                if (w >= 1)     v += hbp[(w - 1) * H + h];
                if (w <= W - 2) v += hbp[w * H + h];
                if (h >= 1)     v += vbp[w * (H - 1) + h - 1];
                if (h <= H - 2) v += vbp[w * (H - 1) + h];
                s[mm] = NLOG2E * v;
            }
            g_PKW[(50 + rw * 2 + jj) * 1024 + t] = __floats2half2_rn(s[0], s[1]);
        }
    }
}

__device__ __forceinline__ unsigned h2u(__half2 v) { return __builtin_bit_cast(unsigned, v); }
__device__ __forceinline__ __half2 u2h(unsigned v) { return __builtin_bit_cast(__half2, v); }

// Pre-activation for row RW: y = bias + wL*pm + wR*nx + v·(shifted current row).
// Writes y into a2[2RW..2RW+1] (deferred sigmoid); carries OLD row value into pm.
#define YROW(RW, NXA, NXB)                                                          \
    {                                                                               \
        const __half2 c2a = a2[2 * (RW)], c2b = a2[2 * (RW) + 1];                   \
        const unsigned P1 = __builtin_amdgcn_perm(h2u(c2a), LU[(RW) >> 1],          \
                              ((RW) & 1) ? 0x05040302u : 0x05040100u);              \
        const unsigned P2 = __builtin_amdgcn_perm(h2u(c2b), h2u(c2a), 0x05040302u); \
        const unsigned P3 = __builtin_amdgcn_perm(RD[(RW) >> 1], h2u(c2b),          \
                              ((RW) & 1) ? 0x07060302u : 0x05040302u);              \
        __half2 ya = pk[50 + 2 * (RW)];                                             \
        ya = __hfma2(pk[2 * (RW)],     pmA,     ya);                                \
        ya = __hfma2(pk[2 * (RW) + 2], NXA,     ya);                                \
        ya = __hfma2(pk[18 + (RW)],    u2h(P1), ya);                                \
        ya = __hfma2(pk[34 + (RW)],    u2h(P2), ya);                                \
        __half2 yb = pk[51 + 2 * (RW)];                                             \
        yb = __hfma2(pk[2 * (RW) + 1], pmB,     yb);                                \
        yb = __hfma2(pk[2 * (RW) + 3], NXB,     yb);                                \
        yb = __hfma2(pk[26 + (RW)],    u2h(P2), yb);                                \
        yb = __hfma2(pk[42 + (RW)],    u2h(P3), yb);                                \
        a2[2 * (RW)] = ya; a2[2 * (RW) + 1] = yb;                                   \
        pmA = c2a; pmB = c2b;                                                       \
    }

// In-place sigmoid of row RW's two y words: sig = rcp(1 + 2^y).
#define SROW(RW)                                                                    \
    a2[2 * (RW)]     = h2rcp(__hadd2(one2, h2exp2(a2[2 * (RW)])));                  \
    a2[2 * (RW) + 1] = h2rcp(__hadd2(one2, h2exp2(a2[2 * (RW) + 1])));

// Snapshot lane-edge words from current a2 (2 rows packed per bpermute).
#define LUPACK                                                                         \
    _Pragma("unroll")                                                                  \
    for (int k = 0; k < 4; ++k) {                                                      \
        const unsigned uw =                                                            \
            __builtin_amdgcn_perm(h2u(a2[4 * k + 3]), h2u(a2[4 * k + 1]), 0x07060302u);\
        const unsigned dw =                                                            \
            __builtin_amdgcn_perm(h2u(a2[4 * k + 2]), h2u(a2[4 * k]),     0x05040100u);\
        LU[k] = __builtin_amdgcn_ds_bpermute(addr_up, uw);                             \
        RD[k] = __builtin_amdgcn_ds_bpermute(addr_dn, dw);                             \
    }

__global__ void __launch_bounds__(1024, 4)
grid_iter(const float* __restrict__ x, const float* __restrict__ w_pre,
          const float* __restrict__ b_pre, const float* __restrict__ w_out,
          const float* __restrict__ b_out, float* __restrict__ out) {
    // 34816 B: first {xs[784] | part[4][256]} for the input GEMV, then the
    // double-buffered halo pub[2][34][256] (rows 0/33 permanent zeros).
    __shared__ __align__(16) unsigned char smraw[2 * PUB_HALFS * 2];
    float* xs   = (float*)smraw;
    float* part = (float*)(smraw + K_IN * 4);
    __half* pub = (__half*)smraw;

    const int tid = threadIdx.x, b = blockIdx.x;
    const int p = tid >> 6, lane = tid & 63;
    const int h0 = lane * 4;

    // ---- fused pre-GEMV: pre[j] = b_pre[j] + x[b,:] @ w_pre[:,j] ----
    for (int k = tid; k < K_IN; k += 1024) xs[k] = x[b * K_IN + k];
    __syncthreads();
    {
        const int j = tid & 255, chunk = tid >> 8;     // 4 chunks x 196
        const float* wp = w_pre + j;
        const int k0 = chunk * 196;
        float acc = 0.f;
#pragma unroll 4
        for (int k = 0; k < 196; ++k) acc += xs[k0 + k] * wp[(k0 + k) * H];
        part[chunk * 256 + j] = acc;
    }
    __syncthreads();
    float pr0 = 0.f, pr1 = 0.f, pr2 = 0.f, pr3 = 0.f;
    if (p == 0) {
        const float4 bp = *(const float4*)&b_pre[h0];
        pr0 = bp.x + part[h0]     + part[256 + h0]     + part[512 + h0]     + part[768 + h0];
        pr1 = bp.y + part[h0 + 1] + part[256 + h0 + 1] + part[512 + h0 + 1] + part[768 + h0 + 1];
        pr2 = bp.z + part[h0 + 2] + part[256 + h0 + 2] + part[512 + h0 + 2] + part[768 + h0 + 2];
        pr3 = bp.w + part[h0 + 3] + part[256 + h0 + 3] + part[512 + h0 + 3] + part[768 + h0 + 3];
    }
    __syncthreads();   // part fully consumed; smraw reused as pub

    // ---- weights into registers; zero pub border rows; init act ----
    __half2 pk[NPK];
#pragma unroll
    for (int i = 0; i < NPK; ++i) pk[i] = g_PKW[i * 1024 + tid];

    {   // rows 0 and 33 of both buffers; one half per thread
        const int bsel = tid >> 9, rsel = (tid >> 8) & 1, col = tid & 255;
        pub[(bsel * PUB_ROWS + (rsel ? 33 : 0)) * 256 + col] = __float2half(0.f);
    }

    __half2 a2[16];   // act rows rw=0..7, 2 half2 each (cols h0..h0+3)
#pragma unroll
    for (int i = 0; i < 16; ++i) a2[i] = __floats2half2_rn(0.f, 0.f);
    if (p == 0) { a2[0] = __floats2half2_rn(pr0, pr1); a2[1] = __floats2half2_rn(pr2, pr3); }

    const __half2 one2 = __floats2half2_rn(1.f, 1.f);
    const int addr_up = (lane - 1) << 2;   // bpermute wraps mod 64; edge garbage hits 0-weights
    const int addr_dn = (lane + 1) << 2;
    unsigned LU[4], RD[4];

    // initial publish of act rows 0,7 into buffer 0
    *(uint2*)(pub + (2 * p + 1) * 256 + h0) = make_uint2(h2u(a2[0]),  h2u(a2[1]));
    *(uint2*)(pub + (2 * p + 2) * 256 + h0) = make_uint2(h2u(a2[14]), h2u(a2[15]));
    __syncthreads();

    int off = 0;
#pragma unroll 1
    for (int it = 0; it < ITERS; ++it) {
        __half* pw = pub + off;                    // buffer published last iter
        __half* pn = pub + (off ^ PUB_HALFS);      // buffer for this iter's results
        // halo reads issued immediately after barrier; consumed by rows 7 and 0
        const uint2 hlw = *(const uint2*)(pw + (2 * p) * 256 + h0);      // zeros at p==0
        const uint2 hrw = *(const uint2*)(pw + (2 * p + 3) * 256 + h0);  // zeros at p==15

        LUPACK;   // lane edges of OLD a2 (must precede any overwrite)
        const __half2 s1a = a2[2], s1b = a2[3];    // old row1 (for row0's nx)

        // ---- phase 1: pre-activations, interior first (no halo dependency) ----
        __half2 pmA = a2[0], pmB = a2[1];          // old row0
        YROW(1, a2[4],  a2[5]);
        YROW(2, a2[6],  a2[7]);
        YROW(3, a2[8],  a2[9]);
        YROW(4, a2[10], a2[11]);
        YROW(5, a2[12], a2[13]);
        YROW(6, a2[14], a2[15]);
        YROW(7, u2h(hrw.x), u2h(hrw.y));           // right halo as nx
        pmA = u2h(hlw.x); pmB = u2h(hlw.y);        // left halo as pm for row0
        YROW(0, s1a, s1b);

        // ---- phase 2: sigmoids (independent chains); boundary rows first ----
        SROW(0); SROW(7);
        *(uint2*)(pn + (2 * p + 1) * 256 + h0) = make_uint2(h2u(a2[0]),  h2u(a2[1]));
        *(uint2*)(pn + (2 * p + 2) * 256 + h0) = make_uint2(h2u(a2[14]), h2u(a2[15]));
        SROW(1); SROW(2); SROW(3); SROW(4); SROW(5); SROW(6);

        __syncthreads();
        off ^= PUB_HALFS;
    }

    // out[b] = act[w=126] @ w_out + b_out ; w=126 is p=15, rw=6 -> a2[12..13]
    if (p == 15) {
        const float2 u0 = __half22float2(a2[12]), u1 = __half22float2(a2[13]);
        const float av[4] = {u0.x, u0.y, u1.x, u1.y};
        float acc[NC];
#pragma unroll
        for (int c = 0; c < NC; ++c) acc[c] = 0.f;
#pragma unroll
        for (int j = 0; j < 4; ++j) {
            const float* wr = w_out + (h0 + j) * NC;
#pragma unroll
            for (int c = 0; c < NC; ++c) acc[c] += av[j] * wr[c];
        }
#pragma unroll
        for (int off2 = 32; off2 >= 1; off2 >>= 1)
#pragma unroll
            for (int c = 0; c < NC; ++c) acc[c] += __shfl_down(acc[c], off2, 64);
        if (lane == 0) {
#pragma unroll
            for (int c = 0; c < NC; ++c) out[b * NC + c] = acc[c] + b_out[c];
        }
    }
}

extern "C" void kernel_launch(void* const* d_in, const int* in_sizes, int n_in,
                              void* d_out, int out_size, void* d_ws, size_t ws_size,
                              hipStream_t stream) {
    const float* x     = (const float*)d_in[0];
    const float* w_pre = (const float*)d_in[1];
    const float* b_pre = (const float*)d_in[2];
    const float* hw    = (const float*)d_in[3];
    const float* vw    = (const float*)d_in[4];
    const float* hb    = (const float*)d_in[5];
    const float* vb    = (const float*)d_in[6];
    const float* w_out = (const float*)d_in[7];
    const float* b_out = (const float*)d_in[8];
    float* out = (float*)d_out;

    hipLaunchKernelGGL(build_pack, dim3(16), dim3(64), 0, stream, hw, vw, hb, vb);
    hipLaunchKernelGGL(grid_iter, dim3(B), dim3(1024), 0, stream,
                       x, w_pre, b_pre, w_out, b_out, out);
}

// Round 10
// 35.603 us; speedup vs baseline: 2.6627x; 2.3705x over previous
//
#include <hip/hip_runtime.h>

constexpr int W = 128, H = 256, ITERS = 24, B = 256, NC = 10;
constexpr float NLOG2E = -1.4426950408889634f;   // fold sigmoid exp->exp2 into weights
constexpr int R0 = 96;          // first simulated row; rows R0..127 (32 rows)
constexpr int SLOTS = 34;       // 1 zero + 32 live + 1 zero halo slots

// The reference's output reads only act[:, W-2, :] after ITERS=24 steps. The
// stencil moves information exactly 1 row in w per step, and the only
// x-dependent initial row is w=0, which is 126 > 24 hops from row 126. Hence
// the output is independent of x (identical for every batch element) and is
// determined by the bias/weight-driven dynamics of rows >= 102. Simulating
// rows 96..127 with a zero left boundary is EXACT for row 126 at t=24:
// boundary error at row 95/96 needs >= 31 hops to reach row 126.
__global__ void __launch_bounds__(1024)
solve(const float* __restrict__ hw, const float* __restrict__ vw,
      const float* __restrict__ hb, const float* __restrict__ vb,
      const float* __restrict__ w_out, const float* __restrict__ b_out,
      float* __restrict__ out) {
    __shared__ float pub[2][SLOTS][H];   // double-buffered row exchange, 69632 B
    __shared__ float o_sh[NC];

    const int tid = threadIdx.x;
    const int p = tid >> 6, lane = tid & 63;
    const int h0 = lane * 4;
    const int r0 = R0 + 2 * p;            // this thread's two rows: r0, r0+1

    // zero both buffers once (slots 0 and 33 stay zero = halo boundary)
    for (int i = tid; i < 2 * SLOTS * H; i += 1024) (&pub[0][0][0])[i] = 0.f;

    // ---- per-thread weights (scaled by -log2(e)), fp32, registers ----
    float wL[2][4], wR[2][4], vD[2][4], vU[2][4], bs[2][4];
#pragma unroll
    for (int rr = 0; rr < 2; ++rr) {
        const int r = r0 + rr;            // 97..127, so r-1 >= 96 always valid
        const float4 hwl = *(const float4*)&hw[(r - 1) * H + h0];
        wL[rr][0] = NLOG2E * hwl.x; wL[rr][1] = NLOG2E * hwl.y;
        wL[rr][2] = NLOG2E * hwl.z; wL[rr][3] = NLOG2E * hwl.w;
        if (r <= W - 2) {
            const float4 hwr = *(const float4*)&hw[r * H + h0];
            wR[rr][0] = NLOG2E * hwr.x; wR[rr][1] = NLOG2E * hwr.y;
            wR[rr][2] = NLOG2E * hwr.z; wR[rr][3] = NLOG2E * hwr.w;
        } else {
            wR[rr][0] = wR[rr][1] = wR[rr][2] = wR[rr][3] = 0.f;
        }
#pragma unroll
        for (int j = 0; j < 4; ++j) {
            const int h = h0 + j;
            vD[rr][j] = (h >= 1)     ? NLOG2E * vw[r * (H - 1) + h - 1] : 0.f;
            vU[rr][j] = (h <= H - 2) ? NLOG2E * vw[r * (H - 1) + h]     : 0.f;
            float v = hb[(r - 1) * H + h];
            if (r <= W - 2) v += hb[r * H + h];
            if (h >= 1)     v += vb[r * (H - 1) + h - 1];
            if (h <= H - 2) v += vb[r * (H - 1) + h];
            bs[rr][j] = NLOG2E * v;
        }
    }

    float a[2][4];
#pragma unroll
    for (int rr = 0; rr < 2; ++rr)
#pragma unroll
        for (int j = 0; j < 4; ++j) a[rr][j] = 0.f;

    __syncthreads();   // pub zeroed

    int buf = 0;
#pragma unroll 1
    for (int it = 0; it < ITERS; ++it) {
        // publish current rows into slots 1+2p (r0) and 2+2p (r0+1)
        *(float4*)&pub[buf][1 + 2 * p][h0] = make_float4(a[0][0], a[0][1], a[0][2], a[0][3]);
        *(float4*)&pub[buf][2 + 2 * p][h0] = make_float4(a[1][0], a[1][1], a[1][2], a[1][3]);
        __syncthreads();
        const float4 hl = *(const float4*)&pub[buf][2 * p][h0];      // row r0-1 (0 at p==0)
        const float4 hr = *(const float4*)&pub[buf][3 + 2 * p][h0];  // row r0+2 (0 at p==15)

        // h-edge neighbors via shuffle; wrap garbage is multiplied by 0-weights
        const float l0 = __shfl_up(a[0][3], 1, 64);
        const float l1 = __shfl_up(a[1][3], 1, 64);
        const float e0 = __shfl_down(a[0][0], 1, 64);
        const float e1 = __shfl_down(a[1][0], 1, 64);

        const float c0[4] = {a[0][0], a[0][1], a[0][2], a[0][3]};   // old row r0
        const float c1[4] = {a[1][0], a[1][1], a[1][2], a[1][3]};   // old row r0+1
        const float hlv[4] = {hl.x, hl.y, hl.z, hl.w};
        const float hrv[4] = {hr.x, hr.y, hr.z, hr.w};

        float y[2][4];
#pragma unroll
        for (int j = 0; j < 4; ++j) {
            const float dn0 = (j == 0) ? l0 : c0[j - 1];
            const float up0 = (j == 3) ? e0 : c0[j + 1];
            y[0][j] = bs[0][j] + wL[0][j] * hlv[j] + wR[0][j] * c1[j]
                    + vD[0][j] * dn0 + vU[0][j] * up0;
            const float dn1 = (j == 0) ? l1 : c1[j - 1];
            const float up1 = (j == 3) ? e1 : c1[j + 1];
            y[1][j] = bs[1][j] + wL[1][j] * c0[j] + wR[1][j] * hrv[j]
                    + vD[1][j] * dn1 + vU[1][j] * up1;
        }
#pragma unroll
        for (int rr = 0; rr < 2; ++rr)
#pragma unroll
            for (int j = 0; j < 4; ++j) {
                const float e = __builtin_amdgcn_exp2f(y[rr][j]);
                a[rr][j] = __builtin_amdgcn_rcpf(1.f + e);   // sigmoid (exp folded)
            }
        buf ^= 1;
    }

    // row 126 lives on wave 15 (r0 = 96+30 = 126), a[0]. Reduce to o[10].
    if (p == 15) {
        float acc[NC];
#pragma unroll
        for (int c = 0; c < NC; ++c) acc[c] = 0.f;
#pragma unroll
        for (int j = 0; j < 4; ++j) {
            const float av = a[0][j];
            const float* wr = w_out + (h0 + j) * NC;
#pragma unroll
            for (int c = 0; c < NC; ++c) acc[c] += av * wr[c];
        }
#pragma unroll
        for (int off = 32; off >= 1; off >>= 1)
#pragma unroll
            for (int c = 0; c < NC; ++c) acc[c] += __shfl_down(acc[c], off, 64);
        if (lane == 0) {
#pragma unroll
            for (int c = 0; c < NC; ++c) o_sh[c] = acc[c] + b_out[c];
        }
    }
    __syncthreads();

    // broadcast: out[b][c] = o[c] for all 256 batch rows (2560 floats)
    for (int i = tid; i < B * NC; i += 1024) {
        const int c = i - (i / NC) * NC;
        out[i] = o_sh[c];
    }
}

extern "C" void kernel_launch(void* const* d_in, const int* in_sizes, int n_in,
                              void* d_out, int out_size, void* d_ws, size_t ws_size,
                              hipStream_t stream) {
    const float* hw    = (const float*)d_in[3];
    const float* vw    = (const float*)d_in[4];
    const float* hb    = (const float*)d_in[5];
    const float* vb    = (const float*)d_in[6];
    const float* w_out = (const float*)d_in[7];
    const float* b_out = (const float*)d_in[8];
    float* out = (float*)d_out;

    hipLaunchKernelGGL(solve, dim3(1), dim3(1024), 0, stream,
                       hw, vw, hb, vb, w_out, b_out, out);
}

// Round 11
// 33.341 us; speedup vs baseline: 2.8433x; 1.0679x over previous
//
#include <hip/hip_runtime.h>

constexpr int W = 128, H = 256, ITERS = 24, B = 256, NC = 10;
constexpr float NLOG2E = -1.4426950408889634f;   // fold sigmoid exp->exp2 into weights
constexpr int R0 = 102;         // first simulated row; rows 102..127 (26 rows)
constexpr int NWAVE = 13;       // 13 waves x 2 rows/thread
constexpr int THREADS = NWAVE * 64;   // 832
constexpr int SLOTS = 28;       // slot 0 = frozen zero (row 101), 1..26 live, 27 = zero (row 128)

// The reference's output reads only act[:, W-2, :] after ITERS=24 steps. The
// stencil moves information exactly 1 row in w per step, and the only
// x-dependent initial row is w=0, which is 126 > 24 hops from row 126. Hence
// the output is independent of x (identical for every batch element).
// Simulating rows 102..127 with a frozen-zero row 101 is EXACT for row 126 at
// t=24: the boundary deviates from the true dynamics starting in row 102 at
// t=2, and that error reaches row 102+k only at t=2+k -> row 126 at t=26 > 24.
__global__ void __launch_bounds__(THREADS)
solve(const float* __restrict__ hw, const float* __restrict__ vw,
      const float* __restrict__ hb, const float* __restrict__ vb,
      const float* __restrict__ w_out, const float* __restrict__ b_out,
      float* __restrict__ out) {
    __shared__ float pub[2][SLOTS][H];   // double-buffered row exchange, 57344 B
    __shared__ float o_sh[NC];

    const int tid = threadIdx.x;
    const int p = tid >> 6, lane = tid & 63;
    const int h0 = lane * 4;
    const int r0 = R0 + 2 * p;            // this thread's two rows: r0, r0+1 (102..127)

    // zero only the 4 frozen halo slots (slots 0 and 27, both buffers);
    // live slots are fully overwritten by every publish before being read.
    for (int i = tid; i < 4 * H; i += THREADS) {
        const int k = i >> 8, c = i & 255;
        pub[k >> 1][(k & 1) ? SLOTS - 1 : 0][c] = 0.f;
    }

    // ---- per-thread weights (scaled by -log2(e)), fp32, registers ----
    float wL[2][4], wR[2][4], vD[2][4], vU[2][4], bs[2][4];
#pragma unroll
    for (int rr = 0; rr < 2; ++rr) {
        const int r = r0 + rr;            // 102..127, so r-1 >= 101 always valid for hw
        const float4 hwl = *(const float4*)&hw[(r - 1) * H + h0];
        wL[rr][0] = NLOG2E * hwl.x; wL[rr][1] = NLOG2E * hwl.y;
        wL[rr][2] = NLOG2E * hwl.z; wL[rr][3] = NLOG2E * hwl.w;
        if (r <= W - 2) {
            const float4 hwr = *(const float4*)&hw[r * H + h0];
            wR[rr][0] = NLOG2E * hwr.x; wR[rr][1] = NLOG2E * hwr.y;
            wR[rr][2] = NLOG2E * hwr.z; wR[rr][3] = NLOG2E * hwr.w;
        } else {
            wR[rr][0] = wR[rr][1] = wR[rr][2] = wR[rr][3] = 0.f;
        }
#pragma unroll
        for (int j = 0; j < 4; ++j) {
            const int h = h0 + j;
            vD[rr][j] = (h >= 1)     ? NLOG2E * vw[r * (H - 1) + h - 1] : 0.f;
            vU[rr][j] = (h <= H - 2) ? NLOG2E * vw[r * (H - 1) + h]     : 0.f;
            float v = hb[(r - 1) * H + h];
            if (r <= W - 2) v += hb[r * H + h];
            if (h >= 1)     v += vb[r * (H - 1) + h - 1];
            if (h <= H - 2) v += vb[r * (H - 1) + h];
            bs[rr][j] = NLOG2E * v;
        }
    }

    float a[2][4];
#pragma unroll
    for (int rr = 0; rr < 2; ++rr)
#pragma unroll
        for (int j = 0; j < 4; ++j) a[rr][j] = 0.f;

    __syncthreads();   // halo slots zeroed

    int buf = 0;
#pragma unroll 1
    for (int it = 0; it < ITERS; ++it) {
        // publish current rows into slots 1+2p (r0) and 2+2p (r0+1)
        *(float4*)&pub[buf][1 + 2 * p][h0] = make_float4(a[0][0], a[0][1], a[0][2], a[0][3]);
        *(float4*)&pub[buf][2 + 2 * p][h0] = make_float4(a[1][0], a[1][1], a[1][2], a[1][3]);

        // everything not involving the halo, BEFORE the barrier:
        // h-edge neighbors via shuffle (wrap garbage hits 0-weights at lanes 0/63)
        const float l0 = __shfl_up(a[0][3], 1, 64);
        const float l1 = __shfl_up(a[1][3], 1, 64);
        const float e0 = __shfl_down(a[0][0], 1, 64);
        const float e1 = __shfl_down(a[1][0], 1, 64);

        float y[2][4];
#pragma unroll
        for (int j = 0; j < 4; ++j) {
            const float dn0 = (j == 0) ? l0 : a[0][j - 1];
            const float up0 = (j == 3) ? e0 : a[0][j + 1];
            y[0][j] = bs[0][j] + wR[0][j] * a[1][j] + vD[0][j] * dn0 + vU[0][j] * up0;
            const float dn1 = (j == 0) ? l1 : a[1][j - 1];
            const float up1 = (j == 3) ? e1 : a[1][j + 1];
            y[1][j] = bs[1][j] + wL[1][j] * a[0][j] + vD[1][j] * dn1 + vU[1][j] * up1;
        }

        __syncthreads();
        // post-barrier critical path: one ds_read + ONE fma per row, then sigmoid
        const float4 hl = *(const float4*)&pub[buf][2 * p][h0];      // row r0-1 (zero at p==0)
        const float4 hr = *(const float4*)&pub[buf][3 + 2 * p][h0];  // row r0+2 (zero at p==12)
        const float hlv[4] = {hl.x, hl.y, hl.z, hl.w};
        const float hrv[4] = {hr.x, hr.y, hr.z, hr.w};
#pragma unroll
        for (int j = 0; j < 4; ++j) {
            const float y0 = y[0][j] + wL[0][j] * hlv[j];
            const float y1 = y[1][j] + wR[1][j] * hrv[j];
            a[0][j] = __builtin_amdgcn_rcpf(1.f + __builtin_amdgcn_exp2f(y0));
            a[1][j] = __builtin_amdgcn_rcpf(1.f + __builtin_amdgcn_exp2f(y1));
        }
        buf ^= 1;
    }

    // row 126 lives on wave 12 (r0 = 102+24 = 126), a[0]. Reduce to o[10].
    if (p == NWAVE - 1) {
        float acc[NC];
#pragma unroll
        for (int c = 0; c < NC; ++c) acc[c] = 0.f;
#pragma unroll
        for (int j = 0; j < 4; ++j) {
            const float av = a[0][j];
            const float* wr = w_out + (h0 + j) * NC;
#pragma unroll
            for (int c = 0; c < NC; ++c) acc[c] += av * wr[c];
        }
#pragma unroll
        for (int off = 32; off >= 1; off >>= 1)
#pragma unroll
            for (int c = 0; c < NC; ++c) acc[c] += __shfl_down(acc[c], off, 64);
        if (lane == 0) {
#pragma unroll
            for (int c = 0; c < NC; ++c) o_sh[c] = acc[c] + b_out[c];
        }
    }
    __syncthreads();

    // broadcast: out[b][c] = o[c] for all 256 batch rows (2560 floats)
    for (int i = tid; i < B * NC; i += THREADS) {
        const int c = i - (i / NC) * NC;
        out[i] = o_sh[c];
    }
}

extern "C" void kernel_launch(void* const* d_in, const int* in_sizes, int n_in,
                              void* d_out, int out_size, void* d_ws, size_t ws_size,
                              hipStream_t stream) {
    const float* hw    = (const float*)d_in[3];
    const float* vw    = (const float*)d_in[4];
    const float* hb    = (const float*)d_in[5];
    const float* vb    = (const float*)d_in[6];
    const float* w_out = (const float*)d_in[7];
    const float* b_out = (const float*)d_in[8];
    float* out = (float*)d_out;

    hipLaunchKernelGGL(solve, dim3(1), dim3(THREADS), 0, stream,
                       hw, vw, hb, vb, w_out, b_out, out);
}

// Round 12
// 27.719 us; speedup vs baseline: 3.4199x; 1.2028x over previous
//
#include <hip/hip_runtime.h>

constexpr int W = 128, H = 256, ITERS = 24, B = 256, NC = 10;
constexpr float NLOG2E = -1.4426950408889634f;   // fold sigmoid exp->exp2 into weights
constexpr int R0 = 102;          // first simulated row; rows 102..127 (26 rows)
constexpr int NROWS = 26;
constexpr int NWAVE = 13;        // 13 waves x 2 rows/thread
constexpr int THREADS = NWAVE * 64;   // 832
constexpr int SLOTS = 28;        // slot 0 = frozen zero (row 101), 1..26 live, 27 = zero

// Staged-weight LDS layout (floats), later reused as the pub halo buffer:
//   sHW[26][256] = hw rows 101..126        sHB[26][256] = hb rows 101..126
//   sVW[26][256] = vw rows 102..127 (+0 pad at col 255)
//   sVB[26][256] = vb rows 102..127 (+0 pad at col 255)
constexpr int SEG = NROWS * 256;          // 6656
constexpr int STAGE_FLOATS = 4 * SEG;     // 26624 floats = 106496 B

// The reference's output reads only act[:, W-2, :] after ITERS=24 steps. The
// stencil moves information exactly 1 row in w per step, and the only
// x-dependent initial row is w=0, which is 126 > 24 hops from row 126. Hence
// the output is independent of x (identical for every batch element).
// Simulating rows 102..127 with a frozen-zero row 101 is EXACT for row 126 at
// t=24: boundary error enters row 102 at t=2 and reaches row 102+k at t=2+k
// -> row 126 at t=26 > 24.
__global__ void __launch_bounds__(THREADS)
solve(const float* __restrict__ hw, const float* __restrict__ vw,
      const float* __restrict__ hb, const float* __restrict__ vb,
      const float* __restrict__ w_out, const float* __restrict__ b_out,
      float* __restrict__ out) {
    __shared__ __align__(16) float smem[STAGE_FLOATS];   // 106496 B
    __shared__ float o_sh[NC];

    float* sHW = smem;
    float* sHB = smem + SEG;
    float* sVW = smem + 2 * SEG;
    float* sVB = smem + 3 * SEG;
    float* pub = smem;               // [2][SLOTS][256] = 14336 floats, reused after unpack

    const int tid = threadIdx.x;
    const int p = tid >> 6, lane = tid & 63;
    const int h0 = lane * 4;
    const int r0 = R0 + 2 * p;       // this thread's rows: r0, r0+1 (102..127)

    // ---- coalesced staging: the ONLY global reads of weight data ----
    for (int i = tid; i < NROWS * 64; i += THREADS) {       // hw/hb, aligned float4
        const int r = i >> 6, c4 = (i & 63) << 2;
        *(float4*)&sHW[r * 256 + c4] = *(const float4*)&hw[(101 + r) * H + c4];
        *(float4*)&sHB[r * 256 + c4] = *(const float4*)&hb[(101 + r) * H + c4];
    }
    for (int i = tid; i < NROWS * 256; i += THREADS) {      // vw/vb, dword + zero pad
        const int r = i >> 8, c = i & 255;
        const bool v = (c < H - 1);
        sVW[i] = v ? vw[(102 + r) * (H - 1) + c] : 0.f;
        sVB[i] = v ? vb[(102 + r) * (H - 1) + c] : 0.f;
    }
    __syncthreads();

    // ---- per-thread weights (scaled by -log2(e)) unpacked from LDS ----
    float wL[2][4], wR[2][4], vD[2][4], vU[2][4], bs[2][4];
#pragma unroll
    for (int rr = 0; rr < 2; ++rr) {
        const int r = r0 + rr;       // 102..127
        const int k = r - R0;        // 0..25; sHW[k] = hw[r-1], sVW[k] = vw[r]
        const float4 hwl = *(const float4*)&sHW[k * 256 + h0];
        const float4 hbl = *(const float4*)&sHB[k * 256 + h0];
        float4 hwr = make_float4(0.f, 0.f, 0.f, 0.f);
        float4 hbr = make_float4(0.f, 0.f, 0.f, 0.f);
        if (r <= W - 2) {            // r=127 has no right neighbor weights
            hwr = *(const float4*)&sHW[(k + 1) * 256 + h0];
            hbr = *(const float4*)&sHB[(k + 1) * 256 + h0];
        }
        const float4 vwa = *(const float4*)&sVW[k * 256 + h0];
        const float4 vba = *(const float4*)&sVB[k * 256 + h0];
        const float vwm = (lane > 0) ? sVW[k * 256 + h0 - 1] : 0.f;
        const float vbm = (lane > 0) ? sVB[k * 256 + h0 - 1] : 0.f;
        const float wa[4] = {vwa.x, vwa.y, vwa.z, vwa.w};
        const float ba[4] = {vba.x, vba.y, vba.z, vba.w};
        const float hl[4] = {hwl.x, hwl.y, hwl.z, hwl.w};
        const float hr[4] = {hwr.x, hwr.y, hwr.z, hwr.w};
        const float bl[4] = {hbl.x, hbl.y, hbl.z, hbl.w};
        const float br[4] = {hbr.x, hbr.y, hbr.z, hbr.w};
#pragma unroll
        for (int j = 0; j < 4; ++j) {
            wL[rr][j] = NLOG2E * hl[j];
            wR[rr][j] = NLOG2E * hr[j];
            vD[rr][j] = NLOG2E * ((j == 0) ? vwm : wa[j - 1]);   // vw[r][h-1], 0 at h=0
            vU[rr][j] = NLOG2E * wa[j];                          // vw[r][h], pad 0 at h=255
            bs[rr][j] = NLOG2E * (bl[j] + br[j] + ((j == 0) ? vbm : ba[j - 1]) + ba[j]);
        }
    }
    __syncthreads();   // staging reads done; smem becomes pub

    // zero the frozen halo slots (slots 0 and 27, both buffers); ordered before
    // any halo read by the loop's first __syncthreads()
    for (int i = tid; i < 4 * H; i += THREADS) {
        const int k = i >> 8, c = i & 255;
        pub[((k >> 1) * SLOTS + ((k & 1) ? SLOTS - 1 : 0)) * H + c] = 0.f;
    }

    float a[2][4];
#pragma unroll
    for (int rr = 0; rr < 2; ++rr)
#pragma unroll
        for (int j = 0; j < 4; ++j) a[rr][j] = 0.f;

    int buf = 0;
#pragma unroll 1
    for (int it = 0; it < ITERS; ++it) {
        // publish current rows into slots 1+2p (r0) and 2+2p (r0+1)
        *(float4*)&pub[(buf * SLOTS + 1 + 2 * p) * H + h0] =
            make_float4(a[0][0], a[0][1], a[0][2], a[0][3]);
        *(float4*)&pub[(buf * SLOTS + 2 + 2 * p) * H + h0] =
            make_float4(a[1][0], a[1][1], a[1][2], a[1][3]);

        // everything not involving the halo, BEFORE the barrier
        const float l0 = __shfl_up(a[0][3], 1, 64);
        const float l1 = __shfl_up(a[1][3], 1, 64);
        const float e0 = __shfl_down(a[0][0], 1, 64);
        const float e1 = __shfl_down(a[1][0], 1, 64);

        float y[2][4];
#pragma unroll
        for (int j = 0; j < 4; ++j) {
            const float dn0 = (j == 0) ? l0 : a[0][j - 1];
            const float up0 = (j == 3) ? e0 : a[0][j + 1];
            y[0][j] = bs[0][j] + wR[0][j] * a[1][j] + vD[0][j] * dn0 + vU[0][j] * up0;
            const float dn1 = (j == 0) ? l1 : a[1][j - 1];
            const float up1 = (j == 3) ? e1 : a[1][j + 1];
            y[1][j] = bs[1][j] + wL[1][j] * a[0][j] + vD[1][j] * dn1 + vU[1][j] * up1;
        }

        __syncthreads();
        // post-barrier: one ds_read + ONE fma per row, then sigmoid
        const float4 hl = *(const float4*)&pub[(buf * SLOTS + 2 * p) * H + h0];
        const float4 hr = *(const float4*)&pub[(buf * SLOTS + 3 + 2 * p) * H + h0];
        const float hlv[4] = {hl.x, hl.y, hl.z, hl.w};
        const float hrv[4] = {hr.x, hr.y, hr.z, hr.w};
#pragma unroll
        for (int j = 0; j < 4; ++j) {
            const float y0 = y[0][j] + wL[0][j] * hlv[j];
            const float y1 = y[1][j] + wR[1][j] * hrv[j];
            a[0][j] = __builtin_amdgcn_rcpf(1.f + __builtin_amdgcn_exp2f(y0));
            a[1][j] = __builtin_amdgcn_rcpf(1.f + __builtin_amdgcn_exp2f(y1));
        }
        buf ^= 1;
    }

    // row 126 lives on wave 12 (r0 = 102+24 = 126), a[0]. Reduce to o[10].
    if (p == NWAVE - 1) {
        float acc[NC];
#pragma unroll
        for (int c = 0; c < NC; ++c) acc[c] = 0.f;
#pragma unroll
        for (int j = 0; j < 4; ++j) {
            const float av = a[0][j];
            const float* wr = w_out + (h0 + j) * NC;
#pragma unroll
            for (int c = 0; c < NC; ++c) acc[c] += av * wr[c];
        }
#pragma unroll
        for (int off = 32; off >= 1; off >>= 1)
#pragma unroll
            for (int c = 0; c < NC; ++c) acc[c] += __shfl_down(acc[c], off, 64);
        if (lane == 0) {
#pragma unroll
            for (int c = 0; c < NC; ++c) o_sh[c] = acc[c] + b_out[c];
        }
    }
    __syncthreads();

    // broadcast: out[b][c] = o[c] for all 256 batch rows (2560 floats)
    for (int i = tid; i < B * NC; i += THREADS) {
        const int c = i - (i / NC) * NC;
        out[i] = o_sh[c];
    }
}

extern "C" void kernel_launch(void* const* d_in, const int* in_sizes, int n_in,
                              void* d_out, int out_size, void* d_ws, size_t ws_size,
                              hipStream_t stream) {
    const float* hw    = (const float*)d_in[3];
    const float* vw    = (const float*)d_in[4];
    const float* hb    = (const float*)d_in[5];
    const float* vb    = (const float*)d_in[6];
    const float* w_out = (const float*)d_in[7];
    const float* b_out = (const float*)d_in[8];
    float* out = (float*)d_out;

    hipLaunchKernelGGL(solve, dim3(1), dim3(THREADS), 0, stream,
                       hw, vw, hb, vb, w_out, b_out, out);
}

// Round 13
// 21.942 us; speedup vs baseline: 4.3205x; 1.2633x over previous
//
#include <hip/hip_runtime.h>

constexpr int W = 128, H = 256, ITERS = 24, B = 256, NC = 10;
constexpr float NLOG2E = -1.4426950408889634f;   // fold sigmoid exp->exp2 into weights
constexpr int R0 = 102;          // first simulated row; rows 102..127 (26 rows)
constexpr int NROWS = 26;
constexpr int NWAVE = 13;        // 13 waves x 2 rows/thread
constexpr int THREADS = NWAVE * 64;   // 832
constexpr int SLOTS = 28;        // slot 0 = frozen zero (row 101), 1..26 live, 27 = zero

// Staged-weight LDS layout (floats), later reused as the pub halo buffer:
//   sHW[26][256] = hw rows 101..126        sHB[26][256] = hb rows 101..126
//   sVW[26][256] = vw rows 102..127 (+0 pad at col 255)
//   sVB[26][256] = vb rows 102..127 (+0 pad at col 255)
constexpr int SEG = NROWS * 256;          // 6656
constexpr int STAGE_FLOATS = 4 * SEG;     // 26624 floats = 106496 B

// Cone argument, spatial + temporal:
//  (1) The output reads only act[:, 126, :] after 24 steps; information moves
//      1 w-row per step; the only x-dependent initial row is w=0, 126 hops
//      away -> output is x-independent (identical for every batch element).
//  (2) Simulating rows 102..127 with frozen-zero row 101 is exact for row 126
//      at t=24 (boundary error reaches row 126 at t=26 > 24).
//  (3) TRIANGLE: S_t[r] influences S_24[126] only if 126 - r <= 24 - t, so
//      the update of row r at step t is needed only when r >= 102 + t.
//      Wave p (rows 102+2p, 103+2p) computes only while it <= 2p (0-indexed);
//      the row-102+2p update at it == 2p uses a frozen neighbor, but that
//      value is outside the cone and never read. Inactive waves republish
//      their frozen rows so both halo buffers stay coherent.
__global__ void __launch_bounds__(THREADS)
solve(const float* __restrict__ hw, const float* __restrict__ vw,
      const float* __restrict__ hb, const float* __restrict__ vb,
      const float* __restrict__ w_out, const float* __restrict__ b_out,
      float* __restrict__ out) {
    __shared__ __align__(16) float smem[STAGE_FLOATS];   // 106496 B
    __shared__ float o_sh[NC];

    float* sHW = smem;
    float* sHB = smem + SEG;
    float* sVW = smem + 2 * SEG;
    float* sVB = smem + 3 * SEG;
    float* pub = smem;               // [2][SLOTS][256] = 14336 floats, reused after unpack

    const int tid = threadIdx.x;
    const int p = tid >> 6, lane = tid & 63;
    const int h0 = lane * 4;
    const int r0 = R0 + 2 * p;       // this thread's rows: r0, r0+1 (102..127)

    // ---- coalesced staging: the ONLY global reads of weight data ----
    for (int i = tid; i < NROWS * 64; i += THREADS) {       // hw/hb, aligned float4
        const int r = i >> 6, c4 = (i & 63) << 2;
        *(float4*)&sHW[r * 256 + c4] = *(const float4*)&hw[(101 + r) * H + c4];
        *(float4*)&sHB[r * 256 + c4] = *(const float4*)&hb[(101 + r) * H + c4];
    }
    for (int i = tid; i < NROWS * 256; i += THREADS) {      // vw/vb, dword + zero pad
        const int r = i >> 8, c = i & 255;
        const bool v = (c < H - 1);
        sVW[i] = v ? vw[(102 + r) * (H - 1) + c] : 0.f;
        sVB[i] = v ? vb[(102 + r) * (H - 1) + c] : 0.f;
    }

    // epilogue prefetch (wave 12 only): 40 contiguous floats/lane of w_out
    // (rows h0..h0+3) + b_out, issued ~24 iterations before use.
    float wf[40];
    float bo[NC];
    if (p == NWAVE - 1) {
#pragma unroll
        for (int k = 0; k < 10; ++k) {
            const float4 v = *(const float4*)&w_out[h0 * NC + 4 * k];
            wf[4 * k] = v.x; wf[4 * k + 1] = v.y; wf[4 * k + 2] = v.z; wf[4 * k + 3] = v.w;
        }
#pragma unroll
        for (int c = 0; c < NC; ++c) bo[c] = b_out[c];
    }
    __syncthreads();

    // ---- per-thread weights (scaled by -log2(e)) unpacked from LDS ----
    float wL[2][4], wR[2][4], vD[2][4], vU[2][4], bs[2][4];
#pragma unroll
    for (int rr = 0; rr < 2; ++rr) {
        const int r = r0 + rr;       // 102..127
        const int k = r - R0;        // 0..25; sHW[k] = hw[r-1], sVW[k] = vw[r]
        const float4 hwl = *(const float4*)&sHW[k * 256 + h0];
        const float4 hbl = *(const float4*)&sHB[k * 256 + h0];
        float4 hwr = make_float4(0.f, 0.f, 0.f, 0.f);
        float4 hbr = make_float4(0.f, 0.f, 0.f, 0.f);
        if (r <= W - 2) {            // r=127 has no right neighbor weights
            hwr = *(const float4*)&sHW[(k + 1) * 256 + h0];
            hbr = *(const float4*)&sHB[(k + 1) * 256 + h0];
        }
        const float4 vwa = *(const float4*)&sVW[k * 256 + h0];
        const float4 vba = *(const float4*)&sVB[k * 256 + h0];
        const float vwm = (lane > 0) ? sVW[k * 256 + h0 - 1] : 0.f;
        const float vbm = (lane > 0) ? sVB[k * 256 + h0 - 1] : 0.f;
        const float wa[4] = {vwa.x, vwa.y, vwa.z, vwa.w};
        const float ba[4] = {vba.x, vba.y, vba.z, vba.w};
        const float hl[4] = {hwl.x, hwl.y, hwl.z, hwl.w};
        const float hr[4] = {hwr.x, hwr.y, hwr.z, hwr.w};
        const float bl[4] = {hbl.x, hbl.y, hbl.z, hbl.w};
        const float br[4] = {hbr.x, hbr.y, hbr.z, hbr.w};
#pragma unroll
        for (int j = 0; j < 4; ++j) {
            wL[rr][j] = NLOG2E * hl[j];
            wR[rr][j] = NLOG2E * hr[j];
            vD[rr][j] = NLOG2E * ((j == 0) ? vwm : wa[j - 1]);   // vw[r][h-1], 0 at h=0
            vU[rr][j] = NLOG2E * wa[j];                          // vw[r][h], pad 0 at h=255
            bs[rr][j] = NLOG2E * (bl[j] + br[j] + ((j == 0) ? vbm : ba[j - 1]) + ba[j]);
        }
    }
    __syncthreads();   // staging reads done; smem becomes pub

    // zero the frozen halo slots (slots 0 and 27, both buffers)
    for (int i = tid; i < 4 * H; i += THREADS) {
        const int k = i >> 8, c = i & 255;
        pub[((k >> 1) * SLOTS + ((k & 1) ? SLOTS - 1 : 0)) * H + c] = 0.f;
    }

    float a[2][4];
#pragma unroll
    for (int rr = 0; rr < 2; ++rr)
#pragma unroll
        for (int j = 0; j < 4; ++j) a[rr][j] = 0.f;

    int buf = 0;
#pragma unroll 1
    for (int it = 0; it < ITERS; ++it) {
        // ALWAYS publish (inactive waves republish frozen rows -> both buffers coherent)
        *(float4*)&pub[(buf * SLOTS + 1 + 2 * p) * H + h0] =
            make_float4(a[0][0], a[0][1], a[0][2], a[0][3]);
        *(float4*)&pub[(buf * SLOTS + 2 + 2 * p) * H + h0] =
            make_float4(a[1][0], a[1][1], a[1][2], a[1][3]);

        const bool active = (it <= 2 * p);   // wave-uniform triangle guard
        float y[2][4];
        if (active) {
            // everything not involving the halo, BEFORE the barrier
            const float l0 = __shfl_up(a[0][3], 1, 64);
            const float l1 = __shfl_up(a[1][3], 1, 64);
            const float e0 = __shfl_down(a[0][0], 1, 64);
            const float e1 = __shfl_down(a[1][0], 1, 64);
#pragma unroll
            for (int j = 0; j < 4; ++j) {
                const float dn0 = (j == 0) ? l0 : a[0][j - 1];
                const float up0 = (j == 3) ? e0 : a[0][j + 1];
                y[0][j] = bs[0][j] + wR[0][j] * a[1][j] + vD[0][j] * dn0 + vU[0][j] * up0;
                const float dn1 = (j == 0) ? l1 : a[1][j - 1];
                const float up1 = (j == 3) ? e1 : a[1][j + 1];
                y[1][j] = bs[1][j] + wL[1][j] * a[0][j] + vD[1][j] * dn1 + vU[1][j] * up1;
            }
        }

        __syncthreads();
        if (active) {
            // post-barrier: one ds_read + ONE fma per row, then sigmoid
            const float4 hl = *(const float4*)&pub[(buf * SLOTS + 2 * p) * H + h0];
            const float4 hr = *(const float4*)&pub[(buf * SLOTS + 3 + 2 * p) * H + h0];
            const float hlv[4] = {hl.x, hl.y, hl.z, hl.w};
            const float hrv[4] = {hr.x, hr.y, hr.z, hr.w};
#pragma unroll
            for (int j = 0; j < 4; ++j) {
                const float y0 = y[0][j] + wL[0][j] * hlv[j];
                const float y1 = y[1][j] + wR[1][j] * hrv[j];
                a[0][j] = __builtin_amdgcn_rcpf(1.f + __builtin_amdgcn_exp2f(y0));
                a[1][j] = __builtin_amdgcn_rcpf(1.f + __builtin_amdgcn_exp2f(y1));
            }
        }
        buf ^= 1;
    }

    // row 126 = wave 12's a[0]. Reduce to o[10] with prefetched weights.
    if (p == NWAVE - 1) {
        float acc[NC];
#pragma unroll
        for (int c = 0; c < NC; ++c) acc[c] = 0.f;
#pragma unroll
        for (int j = 0; j < 4; ++j) {
            const float av = a[0][j];
#pragma unroll
            for (int c = 0; c < NC; ++c) acc[c] += av * wf[j * NC + c];
        }
#pragma unroll
        for (int off = 32; off >= 1; off >>= 1)
#pragma unroll
            for (int c = 0; c < NC; ++c) acc[c] += __shfl_down(acc[c], off, 64);
        if (lane == 0) {
#pragma unroll
            for (int c = 0; c < NC; ++c) o_sh[c] = acc[c] + bo[c];
        }
    }
    __syncthreads();

    // broadcast: out[b][c] = o[c] for all 256 batch rows (2560 floats)
    for (int i = tid; i < B * NC; i += THREADS) {
        const int c = i - (i / NC) * NC;
        out[i] = o_sh[c];
    }
}

extern "C" void kernel_launch(void* const* d_in, const int* in_sizes, int n_in,
                              void* d_out, int out_size, void* d_ws, size_t ws_size,
                              hipStream_t stream) {
    const float* hw    = (const float*)d_in[3];
    const float* vw    = (const float*)d_in[4];
    const float* hb    = (const float*)d_in[5];
    const float* vb    = (const float*)d_in[6];
    const float* w_out = (const float*)d_in[7];
    const float* b_out = (const float*)d_in[8];
    float* out = (float*)d_out;

    hipLaunchKernelGGL(solve, dim3(1), dim3(THREADS), 0, stream,
                       hw, vw, hb, vb, w_out, b_out, out);
}

// Round 14
// 20.726 us; speedup vs baseline: 4.5740x; 1.0587x over previous
//
#include <hip/hip_runtime.h>

typedef float v2f __attribute__((ext_vector_type(2)));

constexpr int W = 128, H = 256, ITERS = 24, B = 256, NC = 10;
constexpr float NLOG2E = -1.4426950408889634f;   // fold sigmoid exp->exp2 into weights
constexpr int R0 = 102;          // first simulated row; rows 102..127 (26 rows)
constexpr int NROWS = 26;
constexpr int NWAVE = 13;        // 13 waves x 2 rows/thread
constexpr int THREADS = NWAVE * 64;   // 832
constexpr int SLOTS = 28;        // slot 0 = frozen zero (row 101), 1..26 live, 27 = zero

// Staged-weight LDS layout (floats), later reused as the pub halo buffer.
constexpr int SEG = NROWS * 256;          // 6656
constexpr int STAGE_FLOATS = 4 * SEG;     // 26624 floats = 106496 B

// Cone argument (see R10-R13): output = x-independent; rows 102..127 with a
// frozen-zero row 101 are exact for row 126 at t=24; update of row r at
// iteration it is needed only if r >= 103+it -> wave p active while it <= 2p.
// Publishes of wave p's rows are read by waves p+-1 only while it <= 2p+2.
__global__ void __launch_bounds__(THREADS)
solve(const float* __restrict__ hw, const float* __restrict__ vw,
      const float* __restrict__ hb, const float* __restrict__ vb,
      const float* __restrict__ w_out, const float* __restrict__ b_out,
      float* __restrict__ out) {
    __shared__ __align__(16) float smem[STAGE_FLOATS];   // 106496 B
    __shared__ float o_sh[NC];

    float* sHW = smem;
    float* sHB = smem + SEG;
    float* sVW = smem + 2 * SEG;
    float* sVB = smem + 3 * SEG;
    float* pub = smem;               // [2][SLOTS][256] floats, reused after unpack

    const int tid = threadIdx.x;
    const int p = tid >> 6, lane = tid & 63;
    const int h0 = lane * 4;
    const int r0 = R0 + 2 * p;       // this thread's rows: r0, r0+1 (102..127)

    // ---- coalesced staging: the ONLY global reads of weight data ----
    for (int i = tid; i < NROWS * 64; i += THREADS) {       // hw/hb, aligned float4
        const int r = i >> 6, c4 = (i & 63) << 2;
        *(float4*)&sHW[r * 256 + c4] = *(const float4*)&hw[(101 + r) * H + c4];
        *(float4*)&sHB[r * 256 + c4] = *(const float4*)&hb[(101 + r) * H + c4];
    }
    for (int i = tid; i < NROWS * 256; i += THREADS) {      // vw/vb, dword + zero pad
        const int r = i >> 8, c = i & 255;
        const bool v = (c < H - 1);
        sVW[i] = v ? vw[(102 + r) * (H - 1) + c] : 0.f;
        sVB[i] = v ? vb[(102 + r) * (H - 1) + c] : 0.f;
    }

    // epilogue prefetch (wave 12 only)
    float wf[40];
    float bo[NC];
    if (p == NWAVE - 1) {
#pragma unroll
        for (int k = 0; k < 10; ++k) {
            const float4 v = *(const float4*)&w_out[h0 * NC + 4 * k];
            wf[4 * k] = v.x; wf[4 * k + 1] = v.y; wf[4 * k + 2] = v.z; wf[4 * k + 3] = v.w;
        }
#pragma unroll
        for (int c = 0; c < NC; ++c) bo[c] = b_out[c];
    }
    __syncthreads();

    // ---- per-thread weights (scaled by -log2(e)) unpacked from LDS into
    //      packed v2f pairs: A = cols (h0,h0+1), B = cols (h0+2,h0+3) ----
    v2f wLA[2], wLB[2], wRA[2], wRB[2], vDA[2], vDB[2], vUA[2], vUB[2], bsA[2], bsB[2];
#pragma unroll
    for (int rr = 0; rr < 2; ++rr) {
        const int r = r0 + rr;       // 102..127
        const int k = r - R0;        // 0..25; sHW[k] = hw[r-1], sVW[k] = vw[r]
        const float4 hwl = *(const float4*)&sHW[k * 256 + h0];
        const float4 hbl = *(const float4*)&sHB[k * 256 + h0];
        float4 hwr = make_float4(0.f, 0.f, 0.f, 0.f);
        float4 hbr = make_float4(0.f, 0.f, 0.f, 0.f);
        if (r <= W - 2) {            // r=127 has no right neighbor weights
            hwr = *(const float4*)&sHW[(k + 1) * 256 + h0];
            hbr = *(const float4*)&sHB[(k + 1) * 256 + h0];
        }
        const float4 vwa = *(const float4*)&sVW[k * 256 + h0];
        const float4 vba = *(const float4*)&sVB[k * 256 + h0];
        const float vwm = (lane > 0) ? sVW[k * 256 + h0 - 1] : 0.f;
        const float vbm = (lane > 0) ? sVB[k * 256 + h0 - 1] : 0.f;

        wLA[rr] = (v2f){NLOG2E * hwl.x, NLOG2E * hwl.y};
        wLB[rr] = (v2f){NLOG2E * hwl.z, NLOG2E * hwl.w};
        wRA[rr] = (v2f){NLOG2E * hwr.x, NLOG2E * hwr.y};
        wRB[rr] = (v2f){NLOG2E * hwr.z, NLOG2E * hwr.w};
        vDA[rr] = (v2f){NLOG2E * vwm,   NLOG2E * vwa.x};    // vw[r][h-1] for cols 0,1
        vDB[rr] = (v2f){NLOG2E * vwa.y, NLOG2E * vwa.z};
        vUA[rr] = (v2f){NLOG2E * vwa.x, NLOG2E * vwa.y};    // vw[r][h] (pad 0 at h=255)
        vUB[rr] = (v2f){NLOG2E * vwa.z, NLOG2E * vwa.w};
        bsA[rr] = (v2f){NLOG2E * (hbl.x + hbr.x + vbm   + vba.x),
                        NLOG2E * (hbl.y + hbr.y + vba.x + vba.y)};
        bsB[rr] = (v2f){NLOG2E * (hbl.z + hbr.z + vba.y + vba.z),
                        NLOG2E * (hbl.w + hbr.w + vba.z + vba.w)};
    }
    __syncthreads();   // staging reads done; smem becomes pub

    // zero the frozen halo slots (slots 0 and 27, both buffers)
    for (int i = tid; i < 4 * H; i += THREADS) {
        const int k = i >> 8, c = i & 255;
        pub[((k >> 1) * SLOTS + ((k & 1) ? SLOTS - 1 : 0)) * H + c] = 0.f;
    }

    v2f aA[2], aB[2];                // state: row rr cols (0,1) and (2,3)
#pragma unroll
    for (int rr = 0; rr < 2; ++rr) { aA[rr] = (v2f){0.f, 0.f}; aB[rr] = (v2f){0.f, 0.f}; }

    int buf = 0;
#pragma unroll 1
    for (int it = 0; it < ITERS; ++it) {
        // publish while anyone can still read us (both buffers end coherent)
        if (it <= 2 * p + 2) {
            *(float4*)&pub[(buf * SLOTS + 1 + 2 * p) * H + h0] =
                make_float4(aA[0].x, aA[0].y, aB[0].x, aB[0].y);
            *(float4*)&pub[(buf * SLOTS + 2 + 2 * p) * H + h0] =
                make_float4(aA[1].x, aA[1].y, aB[1].x, aB[1].y);
        }

        const bool active = (it <= 2 * p);   // wave-uniform triangle guard
        v2f yA[2], yB[2];
        if (active) {
            // h-edge neighbors via shuffle (wrap garbage hits 0-weights)
            const float l0 = __shfl_up(aB[0].y, 1, 64);
            const float l1 = __shfl_up(aB[1].y, 1, 64);
            const float e0 = __shfl_down(aA[0].x, 1, 64);
            const float e1 = __shfl_down(aA[1].x, 1, 64);
            // shifted pairs: L=(l,c0), M=(c1,c2) (shared by dnB and upA), R=(c3,e)
            const v2f L0 = (v2f){l0, aA[0].x}, M0 = (v2f){aA[0].y, aB[0].x},
                      R0v = (v2f){aB[0].y, e0};
            const v2f L1 = (v2f){l1, aA[1].x}, M1 = (v2f){aA[1].y, aB[1].x},
                      R1v = (v2f){aB[1].y, e1};
            // packed pre-activations (v_pk_fma_f32 via fp-contract)
            yA[0] = bsA[0] + wRA[0] * aA[1] + vDA[0] * L0 + vUA[0] * M0;
            yB[0] = bsB[0] + wRB[0] * aB[1] + vDB[0] * M0 + vUB[0] * R0v;
            yA[1] = bsA[1] + wLA[1] * aA[0] + vDA[1] * L1 + vUA[1] * M1;
            yB[1] = bsB[1] + wLB[1] * aB[0] + vDB[1] * M1 + vUB[1] * R1v;
        }

        __syncthreads();
        if (active) {
            // post-barrier: one ds_read + ONE pk-fma per row-pair, then sigmoid
            const float4 hl = *(const float4*)&pub[(buf * SLOTS + 2 * p) * H + h0];
            const float4 hr = *(const float4*)&pub[(buf * SLOTS + 3 + 2 * p) * H + h0];
            yA[0] += wLA[0] * (v2f){hl.x, hl.y};
            yB[0] += wLB[0] * (v2f){hl.z, hl.w};
            yA[1] += wRA[1] * (v2f){hr.x, hr.y};
            yB[1] += wRB[1] * (v2f){hr.z, hr.w};
#pragma unroll
            for (int rr = 0; rr < 2; ++rr) {
                aA[rr].x = __builtin_amdgcn_rcpf(1.f + __builtin_amdgcn_exp2f(yA[rr].x));
                aA[rr].y = __builtin_amdgcn_rcpf(1.f + __builtin_amdgcn_exp2f(yA[rr].y));
                aB[rr].x = __builtin_amdgcn_rcpf(1.f + __builtin_amdgcn_exp2f(yB[rr].x));
                aB[rr].y = __builtin_amdgcn_rcpf(1.f + __builtin_amdgcn_exp2f(yB[rr].y));
            }
        }
        buf ^= 1;
    }

    // row 126 = wave 12's row 0. Reduce to o[10] with prefetched weights.
    if (p == NWAVE - 1) {
        const float av[4] = {aA[0].x, aA[0].y, aB[0].x, aB[0].y};
        float acc[NC];
#pragma unroll
        for (int c = 0; c < NC; ++c) acc[c] = 0.f;
#pragma unroll
        for (int j = 0; j < 4; ++j) {
#pragma unroll
            for (int c = 0; c < NC; ++c) acc[c] += av[j] * wf[j * NC + c];
        }
#pragma unroll
        for (int off = 32; off >= 1; off >>= 1)
#pragma unroll
            for (int c = 0; c < NC; ++c) acc[c] += __shfl_down(acc[c], off, 64);
        if (lane == 0) {
#pragma unroll
            for (int c = 0; c < NC; ++c) o_sh[c] = acc[c] + bo[c];
        }
    }
    __syncthreads();

    // broadcast: out[b][c] = o[c] for all 256 batch rows (2560 floats)
    for (int i = tid; i < B * NC; i += THREADS) {
        const int c = i - (i / NC) * NC;
        out[i] = o_sh[c];
    }
}

extern "C" void kernel_launch(void* const* d_in, const int* in_sizes, int n_in,
                              void* d_out, int out_size, void* d_ws, size_t ws_size,
                              hipStream_t stream) {
    const float* hw    = (const float*)d_in[3];
    const float* vw    = (const float*)d_in[4];
    const float* hb    = (const float*)d_in[5];
    const float* vb    = (const float*)d_in[6];
    const float* w_out = (const float*)d_in[7];
    const float* b_out = (const float*)d_in[8];
    float* out = (float*)d_out;

    hipLaunchKernelGGL(solve, dim3(1), dim3(THREADS), 0, stream,
                       hw, vw, hb, vb, w_out, b_out, out);
}